// Round 3
// baseline (1035.697 us; speedup 1.0000x reference)
//
#include <hip/hip_runtime.h>

constexpr int S    = 256;  // window length
constexpr int D    = 32;   // d_model
constexpr int NH   = 4;
constexpr int DH   = 8;
constexpr int DFF  = 64;
constexpr int NL   = 4;
constexpr int IND  = 58;
constexpr int HOUT = 25;
constexpr int TPB  = 256;  // block = 2 windows, 2 tokens/thread

typedef float  f2  __attribute__((ext_vector_type(2)));
typedef __fp16 h2v __attribute__((ext_vector_type(2)));
typedef __fp16 h8v __attribute__((ext_vector_type(8)));

__device__ __forceinline__ unsigned pk2(float a, float b) {
  h2v h = __builtin_amdgcn_cvt_pkrtz(a, b);
  return __builtin_bit_cast(unsigned, h);
}

// packed-fp32 dot product: NF2 float2 elements (v_pk_fma_f32 on gfx90a+)
template<int NF2>
__device__ __forceinline__ float dotp(const float* __restrict__ w,
                                      const float* __restrict__ v) {
  const f2* W = (const f2*)w;
  const f2* V = (const f2*)v;
  f2 a0 = {0.f, 0.f}, a1 = {0.f, 0.f};
#pragma unroll
  for (int i = 0; i < NF2; i += 2) a0 += V[i] * W[i];
#pragma unroll
  for (int i = 1; i < NF2; i += 2) a1 += V[i] * W[i];
  f2 s = a0 + a1;
  return s.x + s.y;
}

__device__ __forceinline__ void lnorm(float* h, const float* __restrict__ g,
                                      const float* __restrict__ b) {
  float s = 0.f;
#pragma unroll
  for (int d = 0; d < D; ++d) s += h[d];
  const float m = s * (1.0f / D);
  float v = 0.f;
#pragma unroll
  for (int d = 0; d < D; ++d) { float c = h[d] - m; v = fmaf(c, c, v); }
  const float inv = rsqrtf(v * (1.0f / D) + 1e-5f);
#pragma unroll
  for (int d = 0; d < D; ++d) h[d] = (h[d] - m) * inv * g[d] + b[d];
}

__device__ __forceinline__ void embed_token(
    const float* __restrict__ xrow, int lay,
    const float* __restrict__ fpw, const float* __restrict__ fpb,
    const float* __restrict__ lemb, const float* __restrict__ fB,
    float* __restrict__ h) {
  float xr[IND];
  const f2* xv = (const f2*)xrow;  // 8B-aligned: row stride 232 B
#pragma unroll
  for (int i = 0; i < 29; ++i) { f2 t = xv[i]; xr[2 * i] = t.x; xr[2 * i + 1] = t.y; }
  const float* le = lemb + lay * D;
  float pe[D];
#pragma unroll
  for (int k = 0; k < 16; ++k) {
    float pr = 6.2831853071795864f *
               (xr[0] * fB[k] + xr[1] * fB[16 + k] + xr[2] * fB[32 + k]);
    float sv, cv;
    sincosf(pr, &sv, &cv);
    pe[k] = sv; pe[16 + k] = cv;
  }
#pragma unroll 4
  for (int d = 0; d < D; ++d)
    h[d] = dotp<29>(fpw + d * IND, xr) + fpb[d] + le[d] + pe[d];
}

__device__ __forceinline__ void qkv_token(
    const float* __restrict__ Wi, const float* __restrict__ Bi,
    const float* __restrict__ h, float* __restrict__ q, float* __restrict__ kv) {
#pragma unroll 4
  for (int o = 0; o < D; ++o)
    q[o] = (dotp<16>(Wi + o * D, h) + Bi[o]) * 0.35355339059327373f;  // fold 1/sqrt(dh)
#pragma unroll 4
  for (int o = 0; o < 2 * D; ++o)
    kv[o] = dotp<16>(Wi + (D + o) * D, h) + Bi[D + o];
}

__device__ __forceinline__ void post_token(
    int l, float* __restrict__ h, const float* __restrict__ acc,
    const float* __restrict__ opw, const float* __restrict__ opb,
    const float* __restrict__ ln1g, const float* __restrict__ ln1b,
    const float* __restrict__ w1, const float* __restrict__ b1,
    const float* __restrict__ w2, const float* __restrict__ b2,
    const float* __restrict__ ln2g, const float* __restrict__ ln2b) {
  const float* Wo = opw + l * D * D;
  const float* Bo = opb + l * D;
  float o2[D];
#pragma unroll 4
  for (int o = 0; o < D; ++o) o2[o] = dotp<16>(Wo + o * D, acc) + Bo[o];
#pragma unroll
  for (int d = 0; d < D; ++d) h[d] += o2[d];
  lnorm(h, ln1g + l * D, ln1b + l * D);
  const float* Wa = w1 + l * DFF * D;
  const float* Ba = b1 + l * DFF;
  float tt[DFF];
#pragma unroll 4
  for (int j = 0; j < DFF; ++j) {
    float tj = dotp<16>(Wa + j * D, h) + Ba[j];
    tt[j] = 0.5f * tj * (1.0f + erff(tj * 0.70710678118654752f));
  }
  const float* Wb = w2 + l * D * DFF;
  const float* Bb = b2 + l * D;
#pragma unroll 4
  for (int d = 0; d < D; ++d) h[d] += dotp<32>(Wb + d * DFF, tt) + Bb[d];
  lnorm(h, ln2g + l * D, ln2b + l * D);
}

// Block = 2 windows (512 tokens), 256 threads, 2 tokens/thread.
// K/V stored f16 in LDS, 128 B/row, chunk index XOR-swizzled by (row>>1)&7.
__global__ void __launch_bounds__(TPB, 1)
spai_fused(const float* __restrict__ x,    const int*   __restrict__ layers,
           const float* __restrict__ fpw,  const float* __restrict__ fpb,
           const float* __restrict__ lemb, const float* __restrict__ fB,
           const float* __restrict__ ipw,  const float* __restrict__ ipb,
           const float* __restrict__ opw,  const float* __restrict__ opb,
           const float* __restrict__ ln1g, const float* __restrict__ ln1b,
           const float* __restrict__ w1,   const float* __restrict__ b1,
           const float* __restrict__ w2,   const float* __restrict__ b2,
           const float* __restrict__ ln2g, const float* __restrict__ ln2b,
           const float* __restrict__ nog,  const float* __restrict__ nob,
           const float* __restrict__ hw,   const float* __restrict__ hb,
           float* __restrict__ out) {
  __shared__ uint4 kvb[512 * 8];  // 64 KB: 512 rows x 8 chunks(16B, f16x8)
  const int tid = threadIdx.x;
  const int wi  = tid >> 7;      // local window (0/1); waves 0-1 -> w0, 2-3 -> w1
  const int swb = tid & 7;       // write-side swizzle = (row>>1)&7 with row=2*tid+tk
  const size_t blk_tok = (size_t)blockIdx.x * 512;

  float h0[D], h1[D];
  embed_token(x + (blk_tok + 2 * tid) * IND,     layers[blk_tok + 2 * tid],
              fpw, fpb, lemb, fB, h0);
  embed_token(x + (blk_tok + 2 * tid + 1) * IND, layers[blk_tok + 2 * tid + 1],
              fpw, fpb, lemb, fB, h1);

  for (int l = 0; l < NL; ++l) {
    const float* Wi = ipw + l * (3 * D) * D;
    const float* Bi = ipb + l * (3 * D);
    float q0[D], q1[D], kv0[2 * D], kv1[2 * D];
    qkv_token(Wi, Bi, h0, q0, kv0);
    qkv_token(Wi, Bi, h1, q1, kv1);

    __syncthreads();  // prior-layer attention readers done
    {
      uint4* r0 = kvb + (size_t)(2 * tid) * 8;
      uint4* r1 = kvb + (size_t)(2 * tid + 1) * 8;
#pragma unroll
      for (int c = 0; c < 8; ++c) {
        r0[c ^ swb] = uint4{pk2(kv0[8 * c], kv0[8 * c + 1]),
                            pk2(kv0[8 * c + 2], kv0[8 * c + 3]),
                            pk2(kv0[8 * c + 4], kv0[8 * c + 5]),
                            pk2(kv0[8 * c + 6], kv0[8 * c + 7])};
        r1[c ^ swb] = uint4{pk2(kv1[8 * c], kv1[8 * c + 1]),
                            pk2(kv1[8 * c + 2], kv1[8 * c + 3]),
                            pk2(kv1[8 * c + 4], kv1[8 * c + 5]),
                            pk2(kv1[8 * c + 6], kv1[8 * c + 7])};
      }
    }
    __syncthreads();

    float acc0[D], acc1[D], l0[NH], l1[NH];
#pragma unroll
    for (int d = 0; d < D; ++d) { acc0[d] = 0.f; acc1[d] = 0.f; }
#pragma unroll
    for (int hh = 0; hh < NH; ++hh) { l0[hh] = 0.f; l1[hh] = 0.f; }

    const uint4* rowb = kvb + (size_t)wi * 256 * 8;
    for (int j = 0; j < S; ++j) {
      const uint4* row = rowb + (size_t)j * 8;
      const int sw = (j >> 1) & 7;
      h8v Kc[4], Vc[4];
#pragma unroll
      for (int c = 0; c < 4; ++c) Kc[c] = __builtin_bit_cast(h8v, row[c ^ sw]);
#pragma unroll
      for (int c = 0; c < 4; ++c) Vc[c] = __builtin_bit_cast(h8v, row[(4 + c) ^ sw]);

      float e0[NH], e1[NH];
#pragma unroll
      for (int hh = 0; hh < NH; ++hh) {
        h8v kh = Kc[hh];
        float s0 = 0.f, s1 = 0.f;
#pragma unroll
        for (int d = 0; d < DH; ++d) {
          float kf = (float)kh[d];  // fuses into v_fma_mix_f32
          s0 = fmaf(kf, q0[hh * DH + d], s0);
          s1 = fmaf(kf, q1[hh * DH + d], s1);
        }
        e0[hh] = __expf(s0); l0[hh] += e0[hh];
        e1[hh] = __expf(s1); l1[hh] += e1[hh];
      }
#pragma unroll
      for (int hh = 0; hh < NH; ++hh) {
        h8v vh = Vc[hh];
#pragma unroll
        for (int d = 0; d < DH; ++d) {
          float vf = (float)vh[d];
          acc0[hh * DH + d] = fmaf(e0[hh], vf, acc0[hh * DH + d]);
          acc1[hh * DH + d] = fmaf(e1[hh], vf, acc1[hh * DH + d]);
        }
      }
    }

#pragma unroll
    for (int hh = 0; hh < NH; ++hh) {
      const float i0 = 1.0f / l0[hh], i1 = 1.0f / l1[hh];
#pragma unroll
      for (int d = 0; d < DH; ++d) {
        acc0[hh * DH + d] *= i0;
        acc1[hh * DH + d] *= i1;
      }
    }

    post_token(l, h0, acc0, opw, opb, ln1g, ln1b, w1, b1, w2, b2, ln2g, ln2b);
    post_token(l, h1, acc1, opw, opb, ln1g, ln1b, w1, b1, w2, b2, ln2g, ln2b);
  }

  lnorm(h0, nog, nob);
  lnorm(h1, nog, nob);

  __syncthreads();  // last attention reads done before reusing kvb
  float* ost = (float*)kvb;  // 512*25 floats = 50 KB <= 64 KB
#pragma unroll 5
  for (int o = 0; o < HOUT; ++o)
    ost[(2 * tid) * HOUT + o] = dotp<16>(hw + o * D, h0) + hb[o];
#pragma unroll 5
  for (int o = 0; o < HOUT; ++o)
    ost[(2 * tid + 1) * HOUT + o] = dotp<16>(hw + o * D, h1) + hb[o];
  __syncthreads();

  f2* og = (f2*)(out + blk_tok * HOUT);
  const f2* os2 = (const f2*)ost;
#pragma unroll
  for (int i = tid; i < 512 * HOUT / 2; i += TPB) og[i] = os2[i];
}

extern "C" void kernel_launch(void* const* d_in, const int* in_sizes, int n_in,
                              void* d_out, int out_size, void* d_ws, size_t ws_size,
                              hipStream_t stream) {
  const float* x    = (const float*)d_in[0];
  const int*   lays = (const int*)  d_in[1];
  const float* fpw  = (const float*)d_in[2];
  const float* fpb  = (const float*)d_in[3];
  const float* lemb = (const float*)d_in[4];
  const float* fB   = (const float*)d_in[5];
  const float* ipw  = (const float*)d_in[6];
  const float* ipb  = (const float*)d_in[7];
  const float* opw  = (const float*)d_in[8];
  const float* opb  = (const float*)d_in[9];
  const float* ln1g = (const float*)d_in[10];
  const float* ln1b = (const float*)d_in[11];
  const float* w1   = (const float*)d_in[12];
  const float* b1   = (const float*)d_in[13];
  const float* w2   = (const float*)d_in[14];
  const float* b2   = (const float*)d_in[15];
  const float* ln2g = (const float*)d_in[16];
  const float* ln2b = (const float*)d_in[17];
  const float* nog  = (const float*)d_in[18];
  const float* nob  = (const float*)d_in[19];
  const float* hw   = (const float*)d_in[20];
  const float* hb   = (const float*)d_in[21];
  float* out = (float*)d_out;

  const int nwin = in_sizes[0] / (S * IND);  // 512 windows
  spai_fused<<<nwin / 2, TPB, 0, stream>>>(x, lays, fpw, fpb, lemb, fB, ipw, ipb,
                                           opw, opb, ln1g, ln1b, w1, b1, w2, b2,
                                           ln2g, ln2b, nog, nob, hw, hb, out);
}

// Round 4
// 1031.534 us; speedup vs baseline: 1.0040x; 1.0040x over previous
//
#include <hip/hip_runtime.h>

constexpr int S    = 256;  // window length
constexpr int D    = 32;   // d_model
constexpr int NH   = 4;
constexpr int DH   = 8;
constexpr int DFF  = 64;
constexpr int NL   = 4;
constexpr int IND  = 58;
constexpr int HOUT = 25;
constexpr int TPB  = 256;  // block = 2 windows, 2 tokens/thread

typedef float  f2  __attribute__((ext_vector_type(2)));
typedef __fp16 h2  __attribute__((ext_vector_type(2)));
typedef __fp16 h8v __attribute__((ext_vector_type(8)));

__device__ __forceinline__ unsigned pk2(float a, float b) {
  h2 h = __builtin_amdgcn_cvt_pkrtz(a, b);
  return __builtin_bit_cast(unsigned, h);
}

// packed-fp32 dot product: NF2 float2 elements (v_pk_fma_f32)
// NOTE: every loop indexing a register array must FULLY unroll, else the
// array is demoted to scratch (round-3 regression: 251 MB of spill writes).
template<int NF2>
__device__ __forceinline__ float dotp(const float* __restrict__ w,
                                      const float* __restrict__ v) {
  const f2* W = (const f2*)w;
  const f2* V = (const f2*)v;
  f2 a0 = {0.f, 0.f}, a1 = {0.f, 0.f};
#pragma unroll
  for (int i = 0; i < NF2; i += 2) a0 += V[i] * W[i];
#pragma unroll
  for (int i = 1; i < NF2; i += 2) a1 += V[i] * W[i];
  f2 s = a0 + a1;
  return s.x + s.y;
}

// 8-wide f16 dot: q4 = 4 packed half2 (register array, const-indexed), kc = K chunk
__device__ __forceinline__ float qk8(const h2* q4, uint4 kc) {
  h2 k0 = __builtin_bit_cast(h2, kc.x), k1 = __builtin_bit_cast(h2, kc.y);
  h2 k2 = __builtin_bit_cast(h2, kc.z), k3 = __builtin_bit_cast(h2, kc.w);
#if __has_builtin(__builtin_amdgcn_fdot2)
  float s = __builtin_amdgcn_fdot2(q4[0], k0, 0.f, false);
  s = __builtin_amdgcn_fdot2(q4[1], k1, s, false);
  s = __builtin_amdgcn_fdot2(q4[2], k2, s, false);
  s = __builtin_amdgcn_fdot2(q4[3], k3, s, false);
  return s;
#else
  float s = 0.f;
  s = fmaf((float)q4[0][0], (float)k0[0], s);
  s = fmaf((float)q4[0][1], (float)k0[1], s);
  s = fmaf((float)q4[1][0], (float)k1[0], s);
  s = fmaf((float)q4[1][1], (float)k1[1], s);
  s = fmaf((float)q4[2][0], (float)k2[0], s);
  s = fmaf((float)q4[2][1], (float)k2[1], s);
  s = fmaf((float)q4[3][0], (float)k3[0], s);
  s = fmaf((float)q4[3][1], (float)k3[1], s);
  return s;
#endif
}

__device__ __forceinline__ void lnorm(float* h, const float* __restrict__ g,
                                      const float* __restrict__ b) {
  float s = 0.f;
#pragma unroll
  for (int d = 0; d < D; ++d) s += h[d];
  const float m = s * (1.0f / D);
  float v = 0.f;
#pragma unroll
  for (int d = 0; d < D; ++d) { float c = h[d] - m; v = fmaf(c, c, v); }
  const float inv = rsqrtf(v * (1.0f / D) + 1e-5f);
#pragma unroll
  for (int d = 0; d < D; ++d) h[d] = (h[d] - m) * inv * g[d] + b[d];
}

__device__ __forceinline__ void embed_token(
    const float* __restrict__ xrow, int lay,
    const float* __restrict__ fpw, const float* __restrict__ fpb,
    const float* __restrict__ lemb, const float* __restrict__ fB,
    float* __restrict__ h) {
  float xr[IND];
  const f2* xv = (const f2*)xrow;  // 8B-aligned: row stride 232 B
#pragma unroll
  for (int i = 0; i < 29; ++i) { f2 t = xv[i]; xr[2 * i] = t.x; xr[2 * i + 1] = t.y; }
  const float* le = lemb + lay * D;
  float pe[D];
#pragma unroll
  for (int k = 0; k < 16; ++k) {
    float pr = 6.2831853071795864f *
               (xr[0] * fB[k] + xr[1] * fB[16 + k] + xr[2] * fB[32 + k]);
    float sv, cv;
    sincosf(pr, &sv, &cv);
    pe[k] = sv; pe[16 + k] = cv;
  }
#pragma unroll
  for (int d = 0; d < D; ++d)
    h[d] = dotp<29>(fpw + d * IND, xr) + fpb[d] + le[d] + pe[d];
}

__device__ __forceinline__ void post_token(
    int l, float* __restrict__ h, const float* __restrict__ acc,
    const float* __restrict__ opw, const float* __restrict__ opb,
    const float* __restrict__ ln1g, const float* __restrict__ ln1b,
    const float* __restrict__ w1, const float* __restrict__ b1,
    const float* __restrict__ w2, const float* __restrict__ b2,
    const float* __restrict__ ln2g, const float* __restrict__ ln2b) {
  const float* Wo = opw + l * D * D;
  const float* Bo = opb + l * D;
#pragma unroll
  for (int o = 0; o < D; ++o) h[o] += dotp<16>(Wo + o * D, acc) + Bo[o];
  lnorm(h, ln1g + l * D, ln1b + l * D);
  const float* Wa = w1 + l * DFF * D;
  const float* Ba = b1 + l * DFF;
  float tt[DFF];
#pragma unroll
  for (int j = 0; j < DFF; ++j) {
    float tj = dotp<16>(Wa + j * D, h) + Ba[j];
    tt[j] = 0.5f * tj * (1.0f + erff(tj * 0.70710678118654752f));
  }
  const float* Wb = w2 + l * D * DFF;
  const float* Bb = b2 + l * D;
#pragma unroll
  for (int d = 0; d < D; ++d) h[d] += dotp<32>(Wb + d * DFF, tt) + Bb[d];
  lnorm(h, ln2g + l * D, ln2b + l * D);
}

// Block = 2 windows (512 tokens), 256 threads, 2 tokens/thread.
// K/V stored f16 in LDS, 128 B/row, chunk index XOR-swizzled by (row>>1)&7.
__global__ void __launch_bounds__(TPB, 1)
spai_fused(const float* __restrict__ x,    const int*   __restrict__ layers,
           const float* __restrict__ fpw,  const float* __restrict__ fpb,
           const float* __restrict__ lemb, const float* __restrict__ fB,
           const float* __restrict__ ipw,  const float* __restrict__ ipb,
           const float* __restrict__ opw,  const float* __restrict__ opb,
           const float* __restrict__ ln1g, const float* __restrict__ ln1b,
           const float* __restrict__ w1,   const float* __restrict__ b1,
           const float* __restrict__ w2,   const float* __restrict__ b2,
           const float* __restrict__ ln2g, const float* __restrict__ ln2b,
           const float* __restrict__ nog,  const float* __restrict__ nob,
           const float* __restrict__ hw,   const float* __restrict__ hb,
           float* __restrict__ out) {
  __shared__ uint4 kvb[512 * 8];  // 64 KB: 512 rows x 8 chunks(16B, f16x8)
  const int tid = threadIdx.x;
  const int wi  = tid >> 7;      // local window (0/1)
  const int swb = tid & 7;       // write-side swizzle = (row>>1)&7, row=2*tid+tk
  const size_t blk_tok = (size_t)blockIdx.x * 512;

  float h0[D], h1[D];
  embed_token(x + (blk_tok + 2 * tid) * IND,     layers[blk_tok + 2 * tid],
              fpw, fpb, lemb, fB, h0);
  embed_token(x + (blk_tok + 2 * tid + 1) * IND, layers[blk_tok + 2 * tid + 1],
              fpw, fpb, lemb, fB, h1);

  for (int l = 0; l < NL; ++l) {
    const float* Wi = ipw + l * (3 * D) * D;
    const float* Bi = ipb + l * (3 * D);

    __syncthreads();  // prior-layer attention readers done
    // ---- K,V: compute chunk-by-chunk straight into LDS (limits liveness) ----
    {
      uint4* r0 = kvb + (size_t)(2 * tid) * 8;
      uint4* r1 = kvb + (size_t)(2 * tid + 1) * 8;
#pragma unroll
      for (int c = 0; c < 8; ++c) {
        float a[8];
#pragma unroll
        for (int e = 0; e < 8; ++e)
          a[e] = dotp<16>(Wi + (D + 8 * c + e) * D, h0) + Bi[D + 8 * c + e];
        r0[c ^ swb] = uint4{pk2(a[0], a[1]), pk2(a[2], a[3]),
                            pk2(a[4], a[5]), pk2(a[6], a[7])};
#pragma unroll
        for (int e = 0; e < 8; ++e)
          a[e] = dotp<16>(Wi + (D + 8 * c + e) * D, h1) + Bi[D + 8 * c + e];
        r1[c ^ swb] = uint4{pk2(a[0], a[1]), pk2(a[2], a[3]),
                            pk2(a[4], a[5]), pk2(a[6], a[7])};
      }
    }
    // ---- Q: f32 compute, fold 1/sqrt(dh), pack to f16 pairs ----
    h2 qp0[16], qp1[16];
#pragma unroll
    for (int o = 0; o < D; o += 2) {
      float qa = (dotp<16>(Wi + o * D, h0) + Bi[o]) * 0.35355339059327373f;
      float qb = (dotp<16>(Wi + (o + 1) * D, h0) + Bi[o + 1]) * 0.35355339059327373f;
      qp0[o >> 1] = __builtin_bit_cast(h2, pk2(qa, qb));
      qa = (dotp<16>(Wi + o * D, h1) + Bi[o]) * 0.35355339059327373f;
      qb = (dotp<16>(Wi + (o + 1) * D, h1) + Bi[o + 1]) * 0.35355339059327373f;
      qp1[o >> 1] = __builtin_bit_cast(h2, pk2(qa, qb));
    }
    __syncthreads();

    float acc0[D], acc1[D], l0[NH], l1[NH];
#pragma unroll
    for (int d = 0; d < D; ++d) { acc0[d] = 0.f; acc1[d] = 0.f; }
#pragma unroll
    for (int hh = 0; hh < NH; ++hh) { l0[hh] = 0.f; l1[hh] = 0.f; }

    const uint4* rowb = kvb + (size_t)wi * 256 * 8;
#pragma unroll 2
    for (int j = 0; j < S; ++j) {
      const uint4* row = rowb + (size_t)j * 8;
      const int sw = (j >> 1) & 7;
      uint4 Kc[4], Vc[4];
#pragma unroll
      for (int c = 0; c < 4; ++c) Kc[c] = row[c ^ sw];
#pragma unroll
      for (int c = 0; c < 4; ++c) Vc[c] = row[(4 + c) ^ sw];

      float e0[NH], e1[NH];
#pragma unroll
      for (int hh = 0; hh < NH; ++hh) {
        e0[hh] = __expf(qk8(qp0 + 4 * hh, Kc[hh]));
        e1[hh] = __expf(qk8(qp1 + 4 * hh, Kc[hh]));
        l0[hh] += e0[hh];
        l1[hh] += e1[hh];
      }
#pragma unroll
      for (int hh = 0; hh < NH; ++hh) {
        h8v vh = __builtin_bit_cast(h8v, Vc[hh]);
#pragma unroll
        for (int d = 0; d < DH; ++d) {
          float vf = (float)vh[d];  // fuses into v_fma_mix_f32
          acc0[hh * DH + d] = fmaf(e0[hh], vf, acc0[hh * DH + d]);
          acc1[hh * DH + d] = fmaf(e1[hh], vf, acc1[hh * DH + d]);
        }
      }
    }

#pragma unroll
    for (int hh = 0; hh < NH; ++hh) {
      const float i0 = 1.0f / l0[hh], i1 = 1.0f / l1[hh];
#pragma unroll
      for (int d = 0; d < DH; ++d) {
        acc0[hh * DH + d] *= i0;
        acc1[hh * DH + d] *= i1;
      }
    }

    post_token(l, h0, acc0, opw, opb, ln1g, ln1b, w1, b1, w2, b2, ln2g, ln2b);
    post_token(l, h1, acc1, opw, opb, ln1g, ln1b, w1, b1, w2, b2, ln2g, ln2b);
  }

  lnorm(h0, nog, nob);
  lnorm(h1, nog, nob);

  __syncthreads();  // last attention reads done before reusing kvb
  float* ost = (float*)kvb;  // 512*25 floats = 50 KB <= 64 KB
#pragma unroll 5
  for (int o = 0; o < HOUT; ++o)  // LDS dest: runtime index is fine
    ost[(2 * tid) * HOUT + o] = dotp<16>(hw + o * D, h0) + hb[o];
#pragma unroll 5
  for (int o = 0; o < HOUT; ++o)
    ost[(2 * tid + 1) * HOUT + o] = dotp<16>(hw + o * D, h1) + hb[o];
  __syncthreads();

  f2* og = (f2*)(out + blk_tok * HOUT);
  const f2* os2 = (const f2*)ost;
  for (int i = tid; i < 512 * HOUT / 2; i += TPB) og[i] = os2[i];
}

extern "C" void kernel_launch(void* const* d_in, const int* in_sizes, int n_in,
                              void* d_out, int out_size, void* d_ws, size_t ws_size,
                              hipStream_t stream) {
  const float* x    = (const float*)d_in[0];
  const int*   lays = (const int*)  d_in[1];
  const float* fpw  = (const float*)d_in[2];
  const float* fpb  = (const float*)d_in[3];
  const float* lemb = (const float*)d_in[4];
  const float* fB   = (const float*)d_in[5];
  const float* ipw  = (const float*)d_in[6];
  const float* ipb  = (const float*)d_in[7];
  const float* opw  = (const float*)d_in[8];
  const float* opb  = (const float*)d_in[9];
  const float* ln1g = (const float*)d_in[10];
  const float* ln1b = (const float*)d_in[11];
  const float* w1   = (const float*)d_in[12];
  const float* b1   = (const float*)d_in[13];
  const float* w2   = (const float*)d_in[14];
  const float* b2   = (const float*)d_in[15];
  const float* ln2g = (const float*)d_in[16];
  const float* ln2b = (const float*)d_in[17];
  const float* nog  = (const float*)d_in[18];
  const float* nob  = (const float*)d_in[19];
  const float* hw   = (const float*)d_in[20];
  const float* hb   = (const float*)d_in[21];
  float* out = (float*)d_out;

  const int nwin = in_sizes[0] / (S * IND);  // 512 windows
  spai_fused<<<nwin / 2, TPB, 0, stream>>>(x, lays, fpw, fpb, lemb, fB, ipw, ipb,
                                           opw, opb, ln1g, ln1b, w1, b1, w2, b2,
                                           ln2g, ln2b, nog, nob, hw, hb, out);
}

// Round 5
// 516.416 us; speedup vs baseline: 2.0056x; 1.9975x over previous
//
#include <hip/hip_runtime.h>

constexpr int S    = 256;
constexpr int D    = 32;
constexpr int NH   = 4;
constexpr int DH   = 8;
constexpr int DFF  = 64;
constexpr int NL   = 4;
constexpr int IND  = 58;
constexpr int HOUT = 25;
constexpr int TPB  = 256;  // 1 window/block, 1 token/thread, wave = head

typedef float  f2 __attribute__((ext_vector_type(2)));
typedef float  f4 __attribute__((ext_vector_type(4)));
typedef __fp16 h2 __attribute__((ext_vector_type(2)));
typedef __fp16 h4 __attribute__((ext_vector_type(4)));
typedef __fp16 h8 __attribute__((ext_vector_type(8)));

// LDS map (bytes), total exactly 64 KB
constexpr int KOFF = 0;      // K A-frags: [h][jt][qs:2][m:16] * 8 B = 16384
constexpr int QOFF = 16384;  // Q B-frags: same layout = 16384
constexpr int VOFF = 32768;  // V^T: 32 rows x 512 B, chunk-XOR-swizzled = 16384
constexpr int OOFF = 49152;  // attn out: [256 tok][32 f16] = 16384

__device__ __forceinline__ unsigned pk2(float a, float b) {
  h2 h = __builtin_amdgcn_cvt_pkrtz(a, b);
  return __builtin_bit_cast(unsigned, h);
}

// packed-fp32 dot (v_pk_fma_f32). All register-array loops must FULLY unroll
// (partial unroll -> scratch demotion, the round-3 251 MB regression).
template<int NF2>
__device__ __forceinline__ float dotp(const float* __restrict__ w,
                                      const float* __restrict__ v) {
  const f2* W = (const f2*)w;
  const f2* V = (const f2*)v;
  f2 a0 = {0.f, 0.f}, a1 = {0.f, 0.f};
#pragma unroll
  for (int i = 0; i < NF2; i += 2) a0 += V[i] * W[i];
#pragma unroll
  for (int i = 1; i < NF2; i += 2) a1 += V[i] * W[i];
  f2 s = a0 + a1;
  return s.x + s.y;
}

__device__ __forceinline__ void lnorm(float* h, const float* __restrict__ g,
                                      const float* __restrict__ b) {
  float s = 0.f;
#pragma unroll
  for (int d = 0; d < D; ++d) s += h[d];
  const float m = s * (1.0f / D);
  float v = 0.f;
#pragma unroll
  for (int d = 0; d < D; ++d) { float c = h[d] - m; v = fmaf(c, c, v); }
  const float inv = rsqrtf(v * (1.0f / D) + 1e-5f);
#pragma unroll
  for (int d = 0; d < D; ++d) h[d] = (h[d] - m) * inv * g[d] + b[d];
}

__device__ __forceinline__ void embed_token(
    const float* __restrict__ xrow, int lay,
    const float* __restrict__ fpw, const float* __restrict__ fpb,
    const float* __restrict__ lemb, const float* __restrict__ fB,
    float* __restrict__ h) {
  float xr[IND];
  const f2* xv = (const f2*)xrow;  // row stride 232 B -> 8-B aligned
#pragma unroll
  for (int i = 0; i < 29; ++i) { f2 t = xv[i]; xr[2 * i] = t.x; xr[2 * i + 1] = t.y; }
  const float* le = lemb + lay * D;
  float pe[D];
#pragma unroll
  for (int k = 0; k < 16; ++k) {
    float pr = 6.2831853071795864f *
               (xr[0] * fB[k] + xr[1] * fB[16 + k] + xr[2] * fB[32 + k]);
    float sv, cv;
    sincosf(pr, &sv, &cv);
    pe[k] = sv; pe[16 + k] = cv;
  }
#pragma unroll
  for (int d = 0; d < D; ++d)
    h[d] = dotp<29>(fpw + d * IND, xr) + fpb[d] + le[d] + pe[d];
}

__device__ __forceinline__ void post_token(
    int l, float* __restrict__ h, const float* __restrict__ acc,
    const float* __restrict__ opw, const float* __restrict__ opb,
    const float* __restrict__ ln1g, const float* __restrict__ ln1b,
    const float* __restrict__ w1, const float* __restrict__ b1,
    const float* __restrict__ w2, const float* __restrict__ b2,
    const float* __restrict__ ln2g, const float* __restrict__ ln2b) {
  const float* Wo = opw + l * D * D;
  const float* Bo = opb + l * D;
#pragma unroll
  for (int o = 0; o < D; ++o) h[o] += dotp<16>(Wo + o * D, acc) + Bo[o];
  lnorm(h, ln1g + l * D, ln1b + l * D);
  const float* Wa = w1 + l * DFF * D;
  const float* Ba = b1 + l * DFF;
  float tt[DFF];
#pragma unroll
  for (int j = 0; j < DFF; ++j) {
    float tj = dotp<16>(Wa + j * D, h) + Ba[j];
    tt[j] = 0.5f * tj * (1.0f + erff(tj * 0.70710678118654752f));
  }
  const float* Wb = w2 + l * D * DFF;
  const float* Bb = b2 + l * D;
#pragma unroll
  for (int d = 0; d < D; ++d) h[d] += dotp<32>(Wb + d * DFF, tt) + Bb[d];
  lnorm(h, ln2g + l * D, ln2b + l * D);
}

__global__ void __launch_bounds__(TPB, 2)
spai_fused(const float* __restrict__ x,    const int*   __restrict__ layers,
           const float* __restrict__ fpw,  const float* __restrict__ fpb,
           const float* __restrict__ lemb, const float* __restrict__ fB,
           const float* __restrict__ ipw,  const float* __restrict__ ipb,
           const float* __restrict__ opw,  const float* __restrict__ opb,
           const float* __restrict__ ln1g, const float* __restrict__ ln1b,
           const float* __restrict__ w1,   const float* __restrict__ b1,
           const float* __restrict__ w2,   const float* __restrict__ b2,
           const float* __restrict__ ln2g, const float* __restrict__ ln2b,
           const float* __restrict__ nog,  const float* __restrict__ nob,
           const float* __restrict__ hw,   const float* __restrict__ hb,
           float* __restrict__ out) {
  __shared__ __align__(16) unsigned char sm[65536];
  const int tid = threadIdx.x;
  const size_t blk_tok = (size_t)blockIdx.x * S;

  float h[D];
  embed_token(x + (blk_tok + tid) * IND, layers[blk_tok + tid],
              fpw, fpb, lemb, fB, h);

  const int it_w = tid >> 4;   // token's i-tile (phase-1 frag addressing)
  const int m_w  = tid & 15;   // token's row within tile

  for (int l = 0; l < NL; ++l) {
    const float* Wi = ipw + l * (3 * D) * D;
    const float* Bi = ipb + l * (3 * D);

    // ---------- phase 1: QKV, written as MFMA fragments ----------
#pragma unroll
    for (int hd = 0; hd < NH; ++hd) {
      float qv[8], kv[8];
#pragma unroll
      for (int e = 0; e < 8; ++e)
        qv[e] = (dotp<16>(Wi + (hd * 8 + e) * D, h) + Bi[hd * 8 + e]) *
                0.35355339059327373f;  // fold 1/sqrt(dh)
#pragma unroll
      for (int e = 0; e < 8; ++e)
        kv[e] = dotp<16>(Wi + (D + hd * 8 + e) * D, h) + Bi[D + hd * 8 + e];
      const int fbase = ((hd * 16 + it_w) * 32 + m_w) * 8;
      *(uint2*)(sm + QOFF + fbase)       = uint2{pk2(qv[0], qv[1]), pk2(qv[2], qv[3])};
      *(uint2*)(sm + QOFF + fbase + 128) = uint2{pk2(qv[4], qv[5]), pk2(qv[6], qv[7])};
      *(uint2*)(sm + KOFF + fbase)       = uint2{pk2(kv[0], kv[1]), pk2(kv[2], kv[3])};
      *(uint2*)(sm + KOFF + fbase + 128) = uint2{pk2(kv[4], kv[5]), pk2(kv[6], kv[7])};
      // V^T rows hd*8+e, col tid; 8-B chunks XOR-swizzled by (row&7)<<1
#pragma unroll
      for (int e = 0; e < 8; ++e) {
        float vv = dotp<16>(Wi + (2 * D + hd * 8 + e) * D, h) + Bi[2 * D + hd * 8 + e];
        const int c = ((tid >> 2) ^ (e << 1)) * 8 + (tid & 3) * 2;
        *(__fp16*)(sm + VOFF + (hd * 8 + e) * 512 + c) = (__fp16)vv;
      }
    }
    __syncthreads();

    // ---------- phase 2: flash attention via mfma_f32_16x16x16_f16 ----------
    {
      const int lane = tid & 63;
      const int hh   = tid >> 6;       // wave = head
      const int m    = lane & 15;
      const int quad = lane >> 4;
      const int qs   = quad & 1;

      // Hoist K A-frags (it-invariant): quads 2,3 are the dh 8->16 zero pad.
      h4 Af[16];
#pragma unroll
      for (int jt = 0; jt < 16; ++jt) {
        uint2 a = *(const uint2*)(sm + KOFF + ((hh * 16 + jt) * 32 + qs * 16 + m) * 8);
        if (quad >= 2) { a.x = 0u; a.y = 0u; }
        Af[jt] = __builtin_bit_cast(h4, a);
      }
      const int vbase = VOFF + (hh * 8 + (m & 7)) * 512;
      const int vkey  = (m & 7) << 1;

#pragma unroll 2
      for (int it = 0; it < 16; ++it) {
        h4 Qf = *(const h4*)(sm + QOFF + ((hh * 16 + it) * 32 + qs * 16 + m) * 8);
        f4 Of = {0.f, 0.f, 0.f, 0.f};
        float lsum = 0.f;
#pragma unroll
        for (int jt = 0; jt < 16; ++jt) {
          // T[j,i] = K·Q^T: C col = i (lane&15), row = j (quad*4+r)
          f4 T = __builtin_amdgcn_mfma_f32_16x16x16f16(
                     Af[jt], Qf, (f4){0.f, 0.f, 0.f, 0.f}, 0, 0, 0);
          float e0 = __expf(T[0]), e1 = __expf(T[1]);
          float e2 = __expf(T[2]), e3 = __expf(T[3]);
          lsum += (e0 + e1) + (e2 + e3);
          uint2 pu{pk2(e0, e1), pk2(e2, e3)};
          h4 P = __builtin_bit_cast(h4, pu);  // C-frag of T == A-frag of P
          h4 Bv = *(const h4*)(sm + vbase + (((jt * 4 + quad) ^ vkey) * 8));
          Of = __builtin_amdgcn_mfma_f32_16x16x16f16(P, Bv, Of, 0, 0, 0);
        }
        lsum += __shfl_xor(lsum, 16);
        lsum += __shfl_xor(lsum, 32);  // every lane: lsum for query i = lane&15
#pragma unroll
        for (int r = 0; r < 4; ++r) {
          // O row i' = quad*4+r needs lsum held at lanes with lane&15 == i'
          float ls = __builtin_bit_cast(
              float, __builtin_amdgcn_ds_bpermute(
                         (quad * 4 + r) << 2, __builtin_bit_cast(int, lsum)));
          float o = Of[r] * __builtin_amdgcn_rcpf(ls);
          if (m < 8) {
            const int tok = it * 16 + quad * 4 + r;
            *(__fp16*)(sm + OOFF + tok * 64 + (hh * 8 + m) * 2) = (__fp16)o;
          }
        }
      }
    }
    __syncthreads();

    // ---------- phase 3: per-token out-proj + LN + FF + LN ----------
    float acc[D];
    {
      const uint4* orow = (const uint4*)(sm + OOFF + tid * 64);
#pragma unroll
      for (int c = 0; c < 4; ++c) {
        h8 v8 = __builtin_bit_cast(h8, orow[c]);
#pragma unroll
        for (int e = 0; e < 8; ++e) acc[c * 8 + e] = (float)v8[e];
      }
    }
    post_token(l, h, acc, opw, opb, ln1g, ln1b, w1, b1, w2, b2, ln2g, ln2b);
  }

  // ---------- final LN + head ----------
  lnorm(h, nog, nob);
  float* hs = (float*)sm;  // 256*25*4 = 25.6 KB over K+Q regions (phase2 done)
#pragma unroll
  for (int o = 0; o < HOUT; ++o)
    hs[tid * HOUT + o] = dotp<16>(hw + o * D, h) + hb[o];
  __syncthreads();
  f2* og = (f2*)(out + blk_tok * HOUT);
  const f2* os2 = (const f2*)hs;
  for (int i = tid; i < S * HOUT / 2; i += TPB) og[i] = os2[i];
}

extern "C" void kernel_launch(void* const* d_in, const int* in_sizes, int n_in,
                              void* d_out, int out_size, void* d_ws, size_t ws_size,
                              hipStream_t stream) {
  const float* x    = (const float*)d_in[0];
  const int*   lays = (const int*)  d_in[1];
  const float* fpw  = (const float*)d_in[2];
  const float* fpb  = (const float*)d_in[3];
  const float* lemb = (const float*)d_in[4];
  const float* fB   = (const float*)d_in[5];
  const float* ipw  = (const float*)d_in[6];
  const float* ipb  = (const float*)d_in[7];
  const float* opw  = (const float*)d_in[8];
  const float* opb  = (const float*)d_in[9];
  const float* ln1g = (const float*)d_in[10];
  const float* ln1b = (const float*)d_in[11];
  const float* w1   = (const float*)d_in[12];
  const float* b1   = (const float*)d_in[13];
  const float* w2   = (const float*)d_in[14];
  const float* b2   = (const float*)d_in[15];
  const float* ln2g = (const float*)d_in[16];
  const float* ln2b = (const float*)d_in[17];
  const float* nog  = (const float*)d_in[18];
  const float* nob  = (const float*)d_in[19];
  const float* hw   = (const float*)d_in[20];
  const float* hb   = (const float*)d_in[21];
  float* out = (float*)d_out;

  const int nwin = in_sizes[0] / (S * IND);  // 512 windows
  spai_fused<<<nwin, TPB, 0, stream>>>(x, lays, fpw, fpb, lemb, fB, ipw, ipb,
                                       opw, opb, ln1g, ln1b, w1, b1, w2, b2,
                                       ln2g, ln2b, nog, nob, hw, hb, out);
}